// Round 6
// baseline (198.413 us; speedup 1.0000x reference)
//
#include <hip/hip_runtime.h>
#include <math.h>

// SelfNorm: out = x*std_w + mean*(mean_w - std_w)   (std cancels from tensor path)
// Latency fix: global_load_lds async DMA -> whole 13KB plane in flight per wave
// with ZERO payload VGPRs (vmcnt queue depth, not VGPR file, limits MLP).
// Per-wave private LDS region -> no __syncthreads anywhere.

typedef float f32x4 __attribute__((ext_vector_type(4)));

constexpr int N_HW   = 56 * 56;     // 3136 floats per (b,c) plane = 784 vec4
constexpr int BLOCK  = 256;         // 4 waves, one plane per wave
constexpr int WAVES  = 4;
constexpr int LDSW   = 13 * 1024;   // per-wave LDS bytes: 12 full 1KB chunks + padded tail
constexpr float EPS  = 1e-5f;

__device__ __forceinline__ void async_load16(const float* g, void* l) {
    __builtin_amdgcn_global_load_lds(
        (const __attribute__((address_space(1))) void*)g,
        (__attribute__((address_space(3))) void*)l,
        16, 0, 0);   // 16B per lane, dest = lds_base + lane*16
}

__global__ __launch_bounds__(BLOCK, 3) void selfnorm_kernel(
    const float* __restrict__ x,
    const float* __restrict__ W1m, const float* __restrict__ b1m,
    const float* __restrict__ W2m, const float* __restrict__ b2m,
    const float* __restrict__ W1s, const float* __restrict__ b1s,
    const float* __restrict__ W2s, const float* __restrict__ b2s,
    float* __restrict__ out)
{
    __shared__ __align__(16) char lds_raw[WAVES * LDSW];   // 53,248 B -> 3 blocks/CU

    const int tid  = threadIdx.x;
    const int wave = tid >> 6;
    const int lane = tid & 63;
    const int plane = blockIdx.x * WAVES + wave;           // 8192 planes
    const long long base = (long long)plane * N_HW;
    const float* __restrict__ src = x + base;
    float* __restrict__ dsts      = out + base;

    char* myLds = lds_raw + wave * LDSW;

    // ---- 1) async DMA: 13 x 1KB chunks, all in flight, no payload VGPRs ----
    #pragma unroll
    for (int k = 0; k < 12; ++k)
        async_load16(src + 4 * (k * 64 + lane), myLds + k * 1024);
    // tail chunk: floats 3072..3135 = 16 vec4s. Lanes >=16 get a clamped dummy
    // address (plane base); their LDS slots fall in the pad and are never read.
    {
        const float* gp = (lane < 16) ? (src + 3072 + 4 * lane) : src;
        async_load16(gp, myLds + 12 * 1024);
    }
    asm volatile("s_waitcnt vmcnt(0)" ::: "memory");  // per-wave; no barrier needed

    // ---- 2) LDS -> regs, accumulate sum / sumsq ----
    const f32x4* lv = (const f32x4*)myLds;
    f32x4 r[12];
    #pragma unroll
    for (int k = 0; k < 12; ++k) r[k] = lv[k * 64 + lane];
    f32x4 rt = (f32x4){0.f, 0.f, 0.f, 0.f};
    if (lane < 16) rt = lv[768 + lane];

    float sum   = (rt.x + rt.y) + (rt.z + rt.w);
    float sumsq = (rt.x * rt.x + rt.y * rt.y) + (rt.z * rt.z + rt.w * rt.w);
    #pragma unroll
    for (int k = 0; k < 12; ++k) {
        sum   += (r[k].x + r[k].y) + (r[k].z + r[k].w);
        sumsq += (r[k].x * r[k].x + r[k].y * r[k].y)
               + (r[k].z * r[k].z + r[k].w * r[k].w);
    }

    // ---- 3) 64-lane butterfly: every lane gets full-plane sums ----
    #pragma unroll
    for (int off = 1; off < 64; off <<= 1) {
        sum   += __shfl_xor(sum, off, 64);
        sumsq += __shfl_xor(sumsq, off, 64);
    }

    // ---- 4) stats + both tiny MLPs (weights scalarize to s_load) ----
    const float mean = sum * (1.0f / (float)N_HW);
    const float var  = (sumsq - sum * mean) * (1.0f / (float)(N_HW - 1)); // ddof=1
    const float stdv = sqrtf(var + EPS);

    float accm = b2m[0];
    float accs = b2s[0];
    #pragma unroll
    for (int j = 0; j < 16; ++j) {
        float hm = fmaf(W1m[j * 2 + 1], stdv, fmaf(W1m[j * 2], mean, b1m[j]));
        accm = fmaf(W2m[j], fmaxf(hm, 0.f), accm);
        float hs = fmaf(W1s[j * 2 + 1], stdv, fmaf(W1s[j * 2], mean, b1s[j]));
        accs = fmaf(W2s[j], fmaxf(hs, 0.f), accs);
    }
    const float mean_w = 1.0f / (1.0f + expf(-accm));
    const float std_w  = 1.0f / (1.0f + expf(-accs));

    const float a  = std_w;
    const float bb = mean * (mean_w - std_w);

    // ---- 5) apply from registers, coalesced vec4 stores ----
    f32x4* dv = (f32x4*)dsts;
    #pragma unroll
    for (int k = 0; k < 12; ++k) {
        f32x4 o;
        o.x = fmaf(r[k].x, a, bb);
        o.y = fmaf(r[k].y, a, bb);
        o.z = fmaf(r[k].z, a, bb);
        o.w = fmaf(r[k].w, a, bb);
        dv[k * 64 + lane] = o;
    }
    if (lane < 16) {
        f32x4 o;
        o.x = fmaf(rt.x, a, bb);
        o.y = fmaf(rt.y, a, bb);
        o.z = fmaf(rt.z, a, bb);
        o.w = fmaf(rt.w, a, bb);
        dv[768 + lane] = o;
    }
}

extern "C" void kernel_launch(void* const* d_in, const int* in_sizes, int n_in,
                              void* d_out, int out_size, void* d_ws, size_t ws_size,
                              hipStream_t stream) {
    const float* x   = (const float*)d_in[0];
    const float* W1m = (const float*)d_in[1];
    const float* b1m = (const float*)d_in[2];
    const float* W2m = (const float*)d_in[3];
    const float* b2m = (const float*)d_in[4];
    const float* W1s = (const float*)d_in[5];
    const float* b1s = (const float*)d_in[6];
    const float* W2s = (const float*)d_in[7];
    const float* b2s = (const float*)d_in[8];
    float* out = (float*)d_out;

    const int blocks = (32 * 256) / WAVES;   // 8192 planes / 4 = 2048 blocks
    selfnorm_kernel<<<blocks, BLOCK, 0, stream>>>(
        x, W1m, b1m, W2m, b2m, W1s, b1s, W2s, b2s, out);
}